// Round 6
// baseline (270.061 us; speedup 1.0000x reference)
//
#include <hip/hip_runtime.h>
#include <hip/hip_bf16.h>
#include <math.h>

#define DIMSZ 1024
#define NHEAD 16
#define HDIM 64
#define BATCH 2
#define SEQ 2048
#define NROWS (BATCH * SEQ)   // 4096

// softmax in exp2 domain: fold 1/sqrt(64) * log2(e) into Q at conversion
#define QSCALE 0.18033688011112042592f

typedef __attribute__((ext_vector_type(8))) short bf16x8;
typedef __attribute__((ext_vector_type(4))) float f32x4;

__device__ __forceinline__ int swz(int m) { return (m ^ (m >> 2)) & 3; }

__device__ __forceinline__ unsigned hipack(unsigned a, unsigned b) {
    return __builtin_amdgcn_perm(b, a, 0x07060302u);
}

// truncation split: hi = trunc-bf16(x), lo = trunc-bf16(x - hi)
__device__ __forceinline__ void cvt2(float x, float y, unsigned& h, unsigned& l) {
    unsigned ux = __float_as_uint(x), uy = __float_as_uint(y);
    h = hipack(ux, uy);
    float rx = x - __uint_as_float(ux & 0xFFFF0000u);
    float ry = y - __uint_as_float(uy & 0xFFFF0000u);
    l = hipack(__float_as_uint(rx), __float_as_uint(ry));
}

__device__ __forceinline__ void cvt8(const float4& f0, const float4& f1,
                                     uint4& hv, uint4& lv) {
    cvt2(f0.x, f0.y, hv.x, lv.x);
    cvt2(f0.z, f0.w, hv.y, lv.y);
    cvt2(f1.x, f1.y, hv.z, lv.z);
    cvt2(f1.z, f1.w, hv.w, lv.w);
}

__device__ __forceinline__ ushort f2bf(float x) {
    union { __hip_bfloat16 b; ushort u; } cv;
    cv.b = __float2bfloat16(x);
    return cv.u;
}

__device__ __forceinline__ void gld16(const void* g, void* l) {
    __builtin_amdgcn_global_load_lds((const __attribute__((address_space(1))) void*)g,
                                     (__attribute__((address_space(3))) void*)l,
                                     16, 0, 0);
}

// ---------------------------------------------------------------------------
// Fused split-convert of all fp32 operands (x, Wq, Wk, Wv, Wo) in ONE launch.
// Each block converts 2048 elements (256 thr x 8).
// blocks [0,2048): x -> Xhi/Xlo; [2048,2560): Wq; [2560,3072): Wk;
// [3072,3584): Wv; [3584,4096): Wo.
// ---------------------------------------------------------------------------
__global__ __launch_bounds__(256) void convert_all(
    const float* __restrict__ x,
    const float* __restrict__ Wq, const float* __restrict__ Wk,
    const float* __restrict__ Wv, const float* __restrict__ Wo,
    ushort* __restrict__ Xhi, ushort* __restrict__ Xlo,
    ushort* __restrict__ Whi, ushort* __restrict__ Wlo,
    ushort* __restrict__ Wohi, ushort* __restrict__ Wolo)
{
    const int b = blockIdx.x;
    const float* src;
    ushort *hi, *lo;
    size_t off;
    if (b < 2048)      { src = x;  hi = Xhi;  lo = Xlo;  off = (size_t)b * 2048; }
    else if (b < 2560) { src = Wq; hi = Whi;             lo = Wlo;             off = (size_t)(b - 2048) * 2048; }
    else if (b < 3072) { src = Wk; hi = Whi + (1 << 20); lo = Wlo + (1 << 20); off = (size_t)(b - 2560) * 2048; }
    else if (b < 3584) { src = Wv; hi = Whi + 2 * (1 << 20); lo = Wlo + 2 * (1 << 20); off = (size_t)(b - 3072) * 2048; }
    else               { src = Wo; hi = Wohi; lo = Wolo; off = (size_t)(b - 3584) * 2048; }

    const size_t i = off + (size_t)threadIdx.x * 8;
    const float4 f0 = *(const float4*)&src[i];
    const float4 f1 = *(const float4*)&src[i + 4];
    uint4 hv, lv;
    cvt8(f0, f1, hv, lv);
    *(uint4*)&hi[i] = hv;
    *(uint4*)&lo[i] = lv;
}

// ---------------------------------------------------------------------------
// Fused QKV GEMM (split-bf16 MFMA), 48KB LDS -> 3 blocks/CU (768 blocks all
// co-resident, no dispatch tail).
// B (weights): double-buffered LDS via gld16, prefetched one full iter ahead.
// A (X): single 16KB LDS buffer; tile k+1 prefetched into REGISTERS (issued
// before the B gld16s so the pre-ds_write wait is vmcnt(4) = A-only), then
// ds_write-committed after a barrier that orders the A frag reads.
// ---------------------------------------------------------------------------
__global__ __launch_bounds__(256, 3) void qkv_gemm(
    const ushort* __restrict__ Xhi, const ushort* __restrict__ Xlo,
    const ushort* __restrict__ Whi, const ushort* __restrict__ Wlo,
    const float* __restrict__ bq, const float* __restrict__ bk,
    const float* __restrict__ bv,
    ushort* __restrict__ Qb, ushort* __restrict__ Kb, ushort* __restrict__ Vt)
{
    // As: hi[0..4095] lo[4096..8191] (16KB). Bs buf0/buf1: 8192 each (16KB ea).
    __shared__ __align__(16) ushort smem[24576];
    ushort* As = smem;

    const int tid = threadIdx.x;
    const int wave = tid >> 6;
    const int lane = tid & 63;
    const int lm = lane & 15;
    const int lq = lane >> 4;
    const int wy = wave >> 1;
    const int wx = wave & 1;
    const int m0 = blockIdx.x * 128;
    const int nbase = blockIdx.y * 128;

    // A register-load map: thread t -> row ar = t>>1, half ah = t&1 (chunks 2ah, 2ah+1)
    const int ar = tid >> 1;
    const int ah_ = tid & 1;
    const ushort* gah = Xhi + (size_t)(m0 + ar) * DIMSZ + ah_ * 16;
    const ushort* gal = Xlo + (size_t)(m0 + ar) * DIMSZ + ah_ * 16;
    const int wr0 = ar * 32 + (((ah_ * 2 + 0) ^ swz(ar & 15)) << 3);
    const int wr1 = ar * 32 + (((ah_ * 2 + 1) ^ swz(ar & 15)) << 3);

    // B staging map (gld16): thread t -> row r0 = t>>2 (and +64), slot c = t&3
    const int c = tid & 3;
    const int r0 = tid >> 2;
    const int g = c ^ swz(r0 & 15);
    const ushort* gbh = Whi + (size_t)(nbase + r0) * DIMSZ + g * 8;
    const ushort* gbl = Wlo + (size_t)(nbase + r0) * DIMSZ + g * 8;
    const int wofs = wave * 512;

    // frag read offsets
    const int fo = lm * 32 + (((lq ^ swz(lm)) & 3) << 3);
    int aofs[4], bofs[4];
#pragma unroll
    for (int i = 0; i < 4; ++i) {
        aofs[i] = (wy * 64 + i * 16) * 32 + fo;
        bofs[i] = (wx * 64 + i * 16) * 32 + fo;
    }

    f32x4 acc[4][4] = {};

    // prologue: A0 regs -> LDS; B0 -> buf0
    {
        const uint4 h0 = *(const uint4*)(gah);
        const uint4 h1 = *(const uint4*)(gah + 8);
        const uint4 l0 = *(const uint4*)(gal);
        const uint4 l1 = *(const uint4*)(gal + 8);
        ushort* nb = smem + 8192;
        gld16(gbh, nb + wofs);            gld16(gbh + 64 * DIMSZ, nb + 2048 + wofs);
        gld16(gbl, nb + 4096 + wofs);     gld16(gbl + 64 * DIMSZ, nb + 4096 + 2048 + wofs);
        *(uint4*)&As[wr0] = h0;
        *(uint4*)&As[wr1] = h1;
        *(uint4*)&As[4096 + wr0] = l0;
        *(uint4*)&As[4096 + wr1] = l1;
    }

    for (int kk = 0; kk < 32; ++kk) {
        __syncthreads();   // A_kk ds_writes visible; B_kk gld16 drained

        uint4 nh0, nh1, nl0, nl1;
        const bool more = (kk + 1 < 32);
        if (more) {
            const int k0 = (kk + 1) * 32;
            // A loads FIRST (so ds_write below waits vmcnt(4): A only)
            nh0 = *(const uint4*)(gah + k0);
            nh1 = *(const uint4*)(gah + k0 + 8);
            nl0 = *(const uint4*)(gal + k0);
            nl1 = *(const uint4*)(gal + k0 + 8);
            ushort* nb = smem + 8192 + ((kk + 1) & 1) * 8192;
            gld16(gbh + k0, nb + wofs);            gld16(gbh + 64 * DIMSZ + k0, nb + 2048 + wofs);
            gld16(gbl + k0, nb + 4096 + wofs);     gld16(gbl + 64 * DIMSZ + k0, nb + 4096 + 2048 + wofs);
        }

        const ushort* Ah = As;
        const ushort* Al = As + 4096;
        const ushort* Bh = smem + 8192 + (kk & 1) * 8192;
        const ushort* Bl = Bh + 4096;

        bf16x8 ahf[4], alf[4], bhf[4], blf[4];
#pragma unroll
        for (int i = 0; i < 4; ++i) {
            ahf[i] = *(const bf16x8*)&Ah[aofs[i]];
            alf[i] = *(const bf16x8*)&Al[aofs[i]];
            bhf[i] = *(const bf16x8*)&Bh[bofs[i]];
            blf[i] = *(const bf16x8*)&Bl[bofs[i]];
        }
#pragma unroll
        for (int i = 0; i < 4; ++i)
#pragma unroll
            for (int j = 0; j < 4; ++j) {
                acc[i][j] = __builtin_amdgcn_mfma_f32_16x16x32_bf16(ahf[i], bhf[j], acc[i][j], 0, 0, 0);
                acc[i][j] = __builtin_amdgcn_mfma_f32_16x16x32_bf16(ahf[i], blf[j], acc[i][j], 0, 0, 0);
                acc[i][j] = __builtin_amdgcn_mfma_f32_16x16x32_bf16(alf[i], bhf[j], acc[i][j], 0, 0, 0);
            }

        if (more) {
            __syncthreads();   // A frag reads of tile kk complete
            *(uint4*)&As[wr0] = nh0;
            *(uint4*)&As[wr1] = nh1;
            *(uint4*)&As[4096 + nh0.x * 0 + wr0] = nl0;   // keep addr simple below
            *(uint4*)&As[4096 + wr1] = nl1;
        }
    }

    const int mat = blockIdx.y >> 3;      // 0:Q 1:K 2:V (block-uniform)
    const float* bias = (mat == 0) ? bq : (mat == 1) ? bk : bv;
    const int nloc0 = (blockIdx.y & 7) * 128;
    const int b = m0 >> 11;
    const int s0 = m0 & (SEQ - 1);
    ushort* sf = smem;                    // flat reuse for V transpose (17408 <= 24576)

    if (mat == 2) {
        __syncthreads();   // all frag reads done before smem reuse
#pragma unroll
        for (int j = 0; j < 4; ++j) {
            const int nc = nloc0 + wx * 64 + j * 16 + lm;
            const float bb = bias[nc];
            const int d = j * 16 + lm;
#pragma unroll
            for (int i = 0; i < 4; ++i) {
                // permuted position within 32-block: 8*lq + 4*(i&1) + rr
                const int ss = wy * 64 + (i >> 1) * 32 + lq * 8 + (i & 1) * 4;
                ushort4 pk;
                pk.x = f2bf(acc[i][j][0] + bb);
                pk.y = f2bf(acc[i][j][1] + bb);
                pk.z = f2bf(acc[i][j][2] + bb);
                pk.w = f2bf(acc[i][j][3] + bb);
                *(ushort4*)&sf[(wx * 64 + d) * 136 + ss] = pk;
            }
        }
        __syncthreads();
#pragma unroll
        for (int p = 0; p < 8; ++p) {
            const int idx = p * 256 + tid;
            const int row = idx >> 4;          // hh*64 + d
            const int hh = row >> 6;
            const int d = row & 63;
            const int sseg = (idx & 15) * 8;
            const uint4 v = *(const uint4*)&sf[row * 136 + sseg];
            const int hg = (nloc0 >> 6) + hh;
            *(uint4*)&Vt[((size_t)(b * NHEAD + hg) * HDIM + d) * SEQ + s0 + sseg] = v;
        }
    } else {
        ushort* dst = (mat == 0) ? Qb : Kb;
        const float sc = (mat == 0) ? QSCALE : 1.0f;
#pragma unroll
        for (int j = 0; j < 4; ++j) {
            const int nc = nloc0 + wx * 64 + j * 16 + lm;
            const float bb = bias[nc];
            const int h = nc >> 6;
            const int d = nc & 63;
#pragma unroll
            for (int i = 0; i < 4; ++i) {
                const int mb = m0 + wy * 64 + i * 16 + lq * 4;
                const int s = mb & (SEQ - 1);
                const int bh = b * NHEAD + h;
#pragma unroll
                for (int rr = 0; rr < 4; ++rr)
                    dst[((size_t)bh * SEQ + s + rr) * HDIM + d] = f2bf((acc[i][j][rr] + bb) * sc);
            }
        }
    }
}

// ---------------------------------------------------------------------------
// MFMA flash attention, S^T formulation (unchanged from round 5).
// ---------------------------------------------------------------------------
__global__ __launch_bounds__(256) void flash_attn_mfma(
    const ushort* __restrict__ Qb, const ushort* __restrict__ Kb,
    const ushort* __restrict__ Vt,
    ushort* __restrict__ CTXhi, ushort* __restrict__ CTXlo)
{
    __shared__ __align__(16) ushort Ks[2][4096];
    __shared__ __align__(16) ushort Vs[2][4096];

    const int tid = threadIdx.x;
    const int w = tid >> 6;
    const int l = tid & 63;
    const int lm = l & 15;
    const int lq = l >> 4;
    const int q0 = blockIdx.x * 128;
    const int bh = blockIdx.y;

    const ushort* Kg = Kb + (size_t)bh * SEQ * HDIM;
    const ushort* Vg = Vt + (size_t)bh * HDIM * SEQ;

    const int srow = w * 8 + (l >> 3);
    const int sc_ = (l & 7) ^ ((l >> 3) & 7);

    bf16x8 qf[2][2];
#pragma unroll
    for (int rt = 0; rt < 2; ++rt)
#pragma unroll
        for (int kt = 0; kt < 2; ++kt)
            qf[rt][kt] = *(const bf16x8*)&Qb[((size_t)bh * SEQ + q0 + w * 32 + rt * 16 + lm) * HDIM + kt * 32 + lq * 8];

    int koff[4][2];
#pragma unroll
    for (int t = 0; t < 4; ++t)
#pragma unroll
        for (int kt = 0; kt < 2; ++kt)
            koff[t][kt] = (t * 16 + lm) * 64 + (((kt * 4 + lq) ^ (lm & 7)) << 3);

    f32x4 o[2][4] = {};
    float l_[2] = {0.0f, 0.0f};

    {
        ushort* kb = &Ks[0][0];
        ushort* vb = &Vs[0][0];
#pragma unroll
        for (int p = 0; p < 2; ++p) {
            const int row = p * 32 + srow;
            gld16(Kg + (size_t)row * HDIM + sc_ * 8, kb + (p * 32 + w * 8) * 64);
            gld16(Vg + (size_t)row * SEQ + sc_ * 8, vb + (p * 32 + w * 8) * 64);
        }
    }

    for (int ch = 0; ch < SEQ / 64; ++ch) {
        __syncthreads();

        if (ch + 1 < SEQ / 64) {
            const int kc = (ch + 1) * 64;
            ushort* kb = &Ks[(ch + 1) & 1][0];
            ushort* vb = &Vs[(ch + 1) & 1][0];
#pragma unroll
            for (int p = 0; p < 2; ++p) {
                const int row = p * 32 + srow;
                gld16(Kg + (size_t)(kc + row) * HDIM + sc_ * 8, kb + (p * 32 + w * 8) * 64);
                gld16(Vg + (size_t)row * SEQ + kc + sc_ * 8, vb + (p * 32 + w * 8) * 64);
            }
        }

        const ushort* kb = &Ks[ch & 1][0];
        const ushort* vb = &Vs[ch & 1][0];

        f32x4 st[2][4] = {};
#pragma unroll
        for (int ct = 0; ct < 4; ++ct)
#pragma unroll
            for (int kt = 0; kt < 2; ++kt) {
                const bf16x8 kf = *(const bf16x8*)&kb[koff[ct][kt]];
#pragma unroll
                for (int rt = 0; rt < 2; ++rt)
                    st[rt][ct] = __builtin_amdgcn_mfma_f32_16x16x32_bf16(kf, qf[rt][kt], st[rt][ct], 0, 0, 0);
            }

#pragma unroll
        for (int rt = 0; rt < 2; ++rt) {
            float ls = 0.0f;
#pragma unroll
            for (int ct = 0; ct < 4; ++ct)
#pragma unroll
                for (int r = 0; r < 4; ++r) {
                    const float p = __builtin_amdgcn_exp2f(st[rt][ct][r]);
                    st[rt][ct][r] = p;
                    ls += p;
                }
            ls += __shfl_xor(ls, 16, 64);
            ls += __shfl_xor(ls, 32, 64);
            l_[rt] += ls;
        }

        bf16x8 pf[2][2];
#pragma unroll
        for (int rt = 0; rt < 2; ++rt)
#pragma unroll
            for (int kt2 = 0; kt2 < 2; ++kt2) {
                union { bf16x8 v; ushort u[8]; } pk;
#pragma unroll
                for (int t = 0; t < 2; ++t)
#pragma unroll
                    for (int r = 0; r < 4; ++r)
                        pk.u[t * 4 + r] = f2bf(st[rt][kt2 * 2 + t][r]);
                pf[rt][kt2] = pk.v;
            }

#pragma unroll
        for (int dt = 0; dt < 4; ++dt)
#pragma unroll
            for (int kt2 = 0; kt2 < 2; ++kt2) {
                const bf16x8 vf = *(const bf16x8*)&vb[koff[dt][kt2]];
#pragma unroll
                for (int rt = 0; rt < 2; ++rt)
                    o[rt][dt] = __builtin_amdgcn_mfma_f32_16x16x32_bf16(pf[rt][kt2], vf, o[rt][dt], 0, 0, 0);
            }
    }

    const int b = bh >> 4;
    const int h = bh & 15;
#pragma unroll
    for (int rt = 0; rt < 2; ++rt) {
        const float linv_me = 1.0f / l_[rt];
#pragma unroll
        for (int r = 0; r < 4; ++r) {
            const float lr = __shfl(linv_me, lq * 4 + r, 64);
            const int srow_ = q0 + w * 32 + rt * 16 + lq * 4 + r;
            const size_t base = ((size_t)b * SEQ + srow_) * DIMSZ + h * HDIM;
#pragma unroll
            for (int dt = 0; dt < 4; ++dt) {
                const float v = o[rt][dt][r] * lr;
                const unsigned uv = __float_as_uint(v);
                CTXhi[base + dt * 16 + lm] = (ushort)(uv >> 16);
                const float res = v - __uint_as_float(uv & 0xFFFF0000u);
                CTXlo[base + dt * 16 + lm] = (ushort)(__float_as_uint(res) >> 16);
            }
        }
    }
}

// ---------------------------------------------------------------------------
// Output projection: pre-split bf16 operands, pure-gld16 double-buffered.
// 64x128 tiles -> 512 blocks; 48KB LDS -> 3 blocks/CU (unchanged from r5).
// ---------------------------------------------------------------------------
__global__ __launch_bounds__(256) void oproj_gemm(
    const ushort* __restrict__ Ahi_g, const ushort* __restrict__ Alo_g,
    const ushort* __restrict__ Bhi_g, const ushort* __restrict__ Blo_g,
    const float* __restrict__ bias, float* __restrict__ out)
{
    __shared__ __align__(16) ushort smem[2][12288];

    const int tid = threadIdx.x;
    const int wave = tid >> 6;
    const int lane = tid & 63;
    const int lm = lane & 15;
    const int lq = lane >> 4;
    const int wy = wave >> 1;
    const int wx = wave & 1;
    const int m0 = blockIdx.x * 64;
    const int n0 = blockIdx.y * 128;

    const int c = tid & 3;
    const int r0 = tid >> 2;
    const int g = c ^ swz(r0 & 15);
    const ushort* gah = Ahi_g + (size_t)(m0 + r0) * DIMSZ + g * 8;
    const ushort* gal = Alo_g + (size_t)(m0 + r0) * DIMSZ + g * 8;
    const ushort* gbh = Bhi_g + (size_t)(n0 + r0) * DIMSZ + g * 8;
    const ushort* gbl = Blo_g + (size_t)(n0 + r0) * DIMSZ + g * 8;
    const int wofs = wave * 512;

    const int fo = lm * 32 + (((lq ^ swz(lm)) & 3) << 3);
    int aofs[2], bofs[4];
#pragma unroll
    for (int i = 0; i < 2; ++i) aofs[i] = (wy * 32 + i * 16) * 32 + fo;
#pragma unroll
    for (int j = 0; j < 4; ++j) bofs[j] = (wx * 64 + j * 16) * 32 + fo;

    f32x4 acc[2][4] = {};

    {
        ushort* b0 = &smem[0][0];
        gld16(gah, b0 + wofs);
        gld16(gal, b0 + 2048 + wofs);
        gld16(gbh, b0 + 4096 + wofs);   gld16(gbh + 64 * DIMSZ, b0 + 4096 + 2048 + wofs);
        gld16(gbl, b0 + 8192 + wofs);   gld16(gbl + 64 * DIMSZ, b0 + 8192 + 2048 + wofs);
    }

    for (int kk = 0; kk < 32; ++kk) {
        __syncthreads();

        if (kk + 1 < 32) {
            const int k0 = (kk + 1) * 32;
            ushort* nb = &smem[(kk + 1) & 1][0];
            gld16(gah + k0, nb + wofs);
            gld16(gal + k0, nb + 2048 + wofs);
            gld16(gbh + k0, nb + 4096 + wofs);   gld16(gbh + 64 * DIMSZ + k0, nb + 4096 + 2048 + wofs);
            gld16(gbl + k0, nb + 8192 + wofs);   gld16(gbl + 64 * DIMSZ + k0, nb + 8192 + 2048 + wofs);
        }

        const ushort* Ah = &smem[kk & 1][0];
        const ushort* Al = Ah + 2048;
        const ushort* Bh = Ah + 4096;
        const ushort* Bl = Ah + 8192;

        bf16x8 ahf[2], alf[2], bhf[4], blf[4];
#pragma unroll
        for (int i = 0; i < 2; ++i) {
            ahf[i] = *(const bf16x8*)&Ah[aofs[i]];
            alf[i] = *(const bf16x8*)&Al[aofs[i]];
        }
#pragma unroll
        for (int j = 0; j < 4; ++j) {
            bhf[j] = *(const bf16x8*)&Bh[bofs[j]];
            blf[j] = *(const bf16x8*)&Bl[bofs[j]];
        }
#pragma unroll
        for (int i = 0; i < 2; ++i)
#pragma unroll
            for (int j = 0; j < 4; ++j) {
                acc[i][j] = __builtin_amdgcn_mfma_f32_16x16x32_bf16(ahf[i], bhf[j], acc[i][j], 0, 0, 0);
                acc[i][j] = __builtin_amdgcn_mfma_f32_16x16x32_bf16(ahf[i], blf[j], acc[i][j], 0, 0, 0);
                acc[i][j] = __builtin_amdgcn_mfma_f32_16x16x32_bf16(alf[i], bhf[j], acc[i][j], 0, 0, 0);
            }
    }

#pragma unroll
    for (int j = 0; j < 4; ++j) {
        const int nc = n0 + wx * 64 + j * 16 + lm;
        const float bb = bias[nc];
#pragma unroll
        for (int i = 0; i < 2; ++i) {
            const int mb = m0 + wy * 32 + i * 16 + lq * 4;
#pragma unroll
            for (int rr = 0; rr < 4; ++rr)
                out[(size_t)(mb + rr) * DIMSZ + nc] = acc[i][j][rr] + bb;
        }
    }
}

// ---------------------------------------------------------------------------
extern "C" void kernel_launch(void* const* d_in, const int* in_sizes, int n_in,
                              void* d_out, int out_size, void* d_ws, size_t ws_size,
                              hipStream_t stream)
{
    const float* x  = (const float*)d_in[0];
    const float* Wq = (const float*)d_in[1];
    const float* bq = (const float*)d_in[2];
    const float* Wk = (const float*)d_in[3];
    const float* bk = (const float*)d_in[4];
    const float* Wv = (const float*)d_in[5];
    const float* bv = (const float*)d_in[6];
    const float* Wo = (const float*)d_in[7];
    const float* bo = (const float*)d_in[8];
    float* out = (float*)d_out;

    const size_t elems = (size_t)NROWS * DIMSZ;   // 4M
    ushort* Qb    = (ushort*)d_ws;                // 8MB
    ushort* Kb    = Qb + elems;                   // 8MB
    ushort* Vt    = Kb + elems;                   // 8MB
    ushort* CTXhi = Vt + elems;                   // 8MB  (overlay: Xhi)
    ushort* CTXlo = CTXhi + elems;                // 8MB  (overlay: Xlo)
    ushort* Whi   = CTXlo + elems;                // 6MB
    ushort* Wlo   = Whi + 3 * (1 << 20);          // 6MB
    ushort* Wohi  = Wlo + 3 * (1 << 20);          // 2MB
    ushort* Wolo  = Wohi + (1 << 20);             // 2MB  (peak 56MB)
    ushort* Xhi   = CTXhi;                        // dead before flash writes CTX
    ushort* Xlo   = CTXlo;

    convert_all<<<4096, 256, 0, stream>>>(x, Wq, Wk, Wv, Wo,
                                          Xhi, Xlo, Whi, Wlo, Wohi, Wolo);

    qkv_gemm<<<dim3(32, 24), 256, 0, stream>>>(Xhi, Xlo, Whi, Wlo, bq, bk, bv, Qb, Kb, Vt);

    flash_attn_mfma<<<dim3(SEQ / 128, BATCH * NHEAD), 256, 0, stream>>>(Qb, Kb, Vt, CTXhi, CTXlo);

    oproj_gemm<<<dim3(64, 8), 256, 0, stream>>>(CTXhi, CTXlo, Wohi, Wolo, bo, out);
}

// Round 7
// 257.789 us; speedup vs baseline: 1.0476x; 1.0476x over previous
//
#include <hip/hip_runtime.h>
#include <hip/hip_bf16.h>
#include <math.h>

#define DIMSZ 1024
#define NHEAD 16
#define HDIM 64
#define BATCH 2
#define SEQ 2048
#define NROWS (BATCH * SEQ)   // 4096

// softmax in exp2 domain: fold 1/sqrt(64) * log2(e) into Q at conversion
#define QSCALE 0.18033688011112042592f

typedef __attribute__((ext_vector_type(8))) short bf16x8;
typedef __attribute__((ext_vector_type(4))) float f32x4;

__device__ __forceinline__ int swz(int m) { return (m ^ (m >> 2)) & 3; }

__device__ __forceinline__ unsigned hipack(unsigned a, unsigned b) {
    return __builtin_amdgcn_perm(b, a, 0x07060302u);
}

// truncation split: hi = trunc-bf16(x), lo = trunc-bf16(x - hi)
__device__ __forceinline__ void cvt2(float x, float y, unsigned& h, unsigned& l) {
    unsigned ux = __float_as_uint(x), uy = __float_as_uint(y);
    h = hipack(ux, uy);
    float rx = x - __uint_as_float(ux & 0xFFFF0000u);
    float ry = y - __uint_as_float(uy & 0xFFFF0000u);
    l = hipack(__float_as_uint(rx), __float_as_uint(ry));
}

__device__ __forceinline__ void cvt8(const float4& f0, const float4& f1,
                                     uint4& hv, uint4& lv) {
    cvt2(f0.x, f0.y, hv.x, lv.x);
    cvt2(f0.z, f0.w, hv.y, lv.y);
    cvt2(f1.x, f1.y, hv.z, lv.z);
    cvt2(f1.z, f1.w, hv.w, lv.w);
}

__device__ __forceinline__ ushort f2bf(float x) {
    union { __hip_bfloat16 b; ushort u; } cv;
    cv.b = __float2bfloat16(x);
    return cv.u;
}

__device__ __forceinline__ void gld16(const void* g, void* l) {
    __builtin_amdgcn_global_load_lds((const __attribute__((address_space(1))) void*)g,
                                     (__attribute__((address_space(3))) void*)l,
                                     16, 0, 0);
}

// ---------------------------------------------------------------------------
// Fused split-convert of all fp32 operands (x, Wq, Wk, Wv, Wo) in ONE launch.
// ---------------------------------------------------------------------------
__global__ __launch_bounds__(256) void convert_all(
    const float* __restrict__ x,
    const float* __restrict__ Wq, const float* __restrict__ Wk,
    const float* __restrict__ Wv, const float* __restrict__ Wo,
    ushort* __restrict__ Xhi, ushort* __restrict__ Xlo,
    ushort* __restrict__ Whi, ushort* __restrict__ Wlo,
    ushort* __restrict__ Wohi, ushort* __restrict__ Wolo)
{
    const int b = blockIdx.x;
    const float* src;
    ushort *hi, *lo;
    size_t off;
    if (b < 2048)      { src = x;  hi = Xhi;  lo = Xlo;  off = (size_t)b * 2048; }
    else if (b < 2560) { src = Wq; hi = Whi;             lo = Wlo;             off = (size_t)(b - 2048) * 2048; }
    else if (b < 3072) { src = Wk; hi = Whi + (1 << 20); lo = Wlo + (1 << 20); off = (size_t)(b - 2560) * 2048; }
    else if (b < 3584) { src = Wv; hi = Whi + 2 * (1 << 20); lo = Wlo + 2 * (1 << 20); off = (size_t)(b - 3072) * 2048; }
    else               { src = Wo; hi = Wohi; lo = Wolo; off = (size_t)(b - 3584) * 2048; }

    const size_t i = off + (size_t)threadIdx.x * 8;
    const float4 f0 = *(const float4*)&src[i];
    const float4 f1 = *(const float4*)&src[i + 4];
    uint4 hv, lv;
    cvt8(f0, f1, hv, lv);
    *(uint4*)&hi[i] = hv;
    *(uint4*)&lo[i] = lv;
}

// ---------------------------------------------------------------------------
// Fused QKV GEMM (split-bf16 MFMA): round-5 K-loop (pure gld16, full double
// buffer, ONE barrier per iter — proven 82us/40% MfmaUtil), plus vectorized
// epilogues for ALL outputs (LDS transpose -> uint4 coalesced stores; the
// r5 Q/K path's 64 scalar 2B global stores/thread were ~30us of VALU/VMEM).
// ---------------------------------------------------------------------------
__global__ __launch_bounds__(256) void qkv_gemm(
    const ushort* __restrict__ Xhi, const ushort* __restrict__ Xlo,
    const ushort* __restrict__ Whi, const ushort* __restrict__ Wlo,
    const float* __restrict__ bq, const float* __restrict__ bk,
    const float* __restrict__ bv,
    ushort* __restrict__ Qb, ushort* __restrict__ Kb, ushort* __restrict__ Vt)
{
    // per buffer: Ah[4096] Al[4096] Bh[4096] Bl[4096] ushorts = 32KB; x2 = 64KB
    // epilogue reuse: flat 128 x 136 ushort tile (34KB)
    __shared__ __align__(16) ushort smem[2][16384];

    const int tid = threadIdx.x;
    const int wave = tid >> 6;
    const int lane = tid & 63;
    const int lm = lane & 15;
    const int lq = lane >> 4;
    const int wy = wave >> 1;
    const int wx = wave & 1;
    const int m0 = blockIdx.x * 128;
    const int nbase = blockIdx.y * 128;

    // staging map: thread t -> row r0 = t>>2 (and r0+64), LDS slot c = t&3,
    // global chunk g = c ^ swz(r0&15)
    const int c = tid & 3;
    const int r0 = tid >> 2;
    const int g = c ^ swz(r0 & 15);
    const ushort* gah = Xhi + (size_t)(m0 + r0) * DIMSZ + g * 8;
    const ushort* gal = Xlo + (size_t)(m0 + r0) * DIMSZ + g * 8;
    const ushort* gbh = Whi + (size_t)(nbase + r0) * DIMSZ + g * 8;
    const ushort* gbl = Wlo + (size_t)(nbase + r0) * DIMSZ + g * 8;
    const int wofs = wave * 512;

    // frag read offsets
    const int fo = lm * 32 + (((lq ^ swz(lm)) & 3) << 3);
    int aofs[4], bofs[4];
#pragma unroll
    for (int i = 0; i < 4; ++i) {
        aofs[i] = (wy * 64 + i * 16) * 32 + fo;
        bofs[i] = (wx * 64 + i * 16) * 32 + fo;
    }

    f32x4 acc[4][4] = {};

    // stage k-tile 0 into buffer 0
    {
        ushort* b0 = &smem[0][0];
        gld16(gah, b0 + wofs);                  gld16(gah + 64 * DIMSZ, b0 + 2048 + wofs);
        gld16(gal, b0 + 4096 + wofs);           gld16(gal + 64 * DIMSZ, b0 + 4096 + 2048 + wofs);
        gld16(gbh, b0 + 8192 + wofs);           gld16(gbh + 64 * DIMSZ, b0 + 8192 + 2048 + wofs);
        gld16(gbl, b0 + 12288 + wofs);          gld16(gbl + 64 * DIMSZ, b0 + 12288 + 2048 + wofs);
    }

    for (int kk = 0; kk < 32; ++kk) {
        __syncthreads();   // buffer kk&1 staged (prefetch had a full iter in flight)

        if (kk + 1 < 32) {
            const int k0 = (kk + 1) * 32;
            ushort* nb = &smem[(kk + 1) & 1][0];
            gld16(gah + k0, nb + wofs);                  gld16(gah + 64 * DIMSZ + k0, nb + 2048 + wofs);
            gld16(gal + k0, nb + 4096 + wofs);           gld16(gal + 64 * DIMSZ + k0, nb + 4096 + 2048 + wofs);
            gld16(gbh + k0, nb + 8192 + wofs);           gld16(gbh + 64 * DIMSZ + k0, nb + 8192 + 2048 + wofs);
            gld16(gbl + k0, nb + 12288 + wofs);          gld16(gbl + 64 * DIMSZ + k0, nb + 12288 + 2048 + wofs);
        }

        const ushort* Ah = &smem[kk & 1][0];
        const ushort* Al = Ah + 4096;
        const ushort* Bh = Ah + 8192;
        const ushort* Bl = Ah + 12288;

        bf16x8 ahf[4], alf[4], bhf[4], blf[4];
#pragma unroll
        for (int i = 0; i < 4; ++i) {
            ahf[i] = *(const bf16x8*)&Ah[aofs[i]];
            alf[i] = *(const bf16x8*)&Al[aofs[i]];
            bhf[i] = *(const bf16x8*)&Bh[bofs[i]];
            blf[i] = *(const bf16x8*)&Bl[bofs[i]];
        }
#pragma unroll
        for (int i = 0; i < 4; ++i)
#pragma unroll
            for (int j = 0; j < 4; ++j) {
                acc[i][j] = __builtin_amdgcn_mfma_f32_16x16x32_bf16(ahf[i], bhf[j], acc[i][j], 0, 0, 0);
                acc[i][j] = __builtin_amdgcn_mfma_f32_16x16x32_bf16(ahf[i], blf[j], acc[i][j], 0, 0, 0);
                acc[i][j] = __builtin_amdgcn_mfma_f32_16x16x32_bf16(alf[i], bhf[j], acc[i][j], 0, 0, 0);
            }
    }

    const int mat = blockIdx.y >> 3;      // 0:Q 1:K 2:V (block-uniform)
    const float* bias = (mat == 0) ? bq : (mat == 1) ? bk : bv;
    const int nloc0 = (blockIdx.y & 7) * 128;
    const int b = m0 >> 11;
    const int s0 = m0 & (SEQ - 1);
    ushort* sf = &smem[0][0];             // flat reuse (needs 17408 ushorts)

    __syncthreads();   // last iteration's frag reads complete before smem reuse

    if (mat == 2) {
        // ---- V: transpose to [d][s], key-permuted within 32-blocks
#pragma unroll
        for (int j = 0; j < 4; ++j) {
            const int nc = nloc0 + wx * 64 + j * 16 + lm;
            const float bb = bias[nc];
            const int d = j * 16 + lm;
#pragma unroll
            for (int i = 0; i < 4; ++i) {
                // permuted position within 32-block: 8*lq + 4*(i&1) + rr
                const int ss = wy * 64 + (i >> 1) * 32 + lq * 8 + (i & 1) * 4;
                ushort4 pk;
                pk.x = f2bf(acc[i][j][0] + bb);
                pk.y = f2bf(acc[i][j][1] + bb);
                pk.z = f2bf(acc[i][j][2] + bb);
                pk.w = f2bf(acc[i][j][3] + bb);
                *(ushort4*)&sf[(wx * 64 + d) * 136 + ss] = pk;
            }
        }
        __syncthreads();
#pragma unroll
        for (int p = 0; p < 8; ++p) {
            const int idx = p * 256 + tid;
            const int row = idx >> 4;          // hh*64 + d
            const int hh = row >> 6;
            const int d = row & 63;
            const int sseg = (idx & 15) * 8;
            const uint4 v = *(const uint4*)&sf[row * 136 + sseg];
            const int hg = (nloc0 >> 6) + hh;
            *(uint4*)&Vt[((size_t)(b * NHEAD + hg) * HDIM + d) * SEQ + s0 + sseg] = v;
        }
    } else {
        // ---- Q/K: [s][d] tile in LDS (scalar writes), uint4 coalesced out
        ushort* dst = (mat == 0) ? Qb : Kb;
        const float sc = (mat == 0) ? QSCALE : 1.0f;
#pragma unroll
        for (int j = 0; j < 4; ++j) {
            const int col = wx * 64 + j * 16 + lm;      // 0..127
            const float bb = bias[nloc0 + col];
#pragma unroll
            for (int i = 0; i < 4; ++i) {
                const int rbase = wy * 64 + i * 16 + lq * 4;
#pragma unroll
                for (int rr = 0; rr < 4; ++rr)
                    sf[(rbase + rr) * 136 + col] = f2bf((acc[i][j][rr] + bb) * sc);
            }
        }
        __syncthreads();
#pragma unroll
        for (int p = 0; p < 8; ++p) {
            const int idx = p * 256 + tid;
            const int row = idx >> 4;          // local s: 0..127
            const int seg = idx & 15;          // 8-col segment
            const uint4 v = *(const uint4*)&sf[row * 136 + seg * 8];
            const int nc0 = nloc0 + seg * 8;
            const int h = nc0 >> 6;
            const int d = nc0 & 63;
            *(uint4*)&dst[((size_t)(b * NHEAD + h) * SEQ + s0 + row) * HDIM + d] = v;
        }
    }
}

// ---------------------------------------------------------------------------
// MFMA flash attention, S^T formulation (unchanged).
// ---------------------------------------------------------------------------
__global__ __launch_bounds__(256) void flash_attn_mfma(
    const ushort* __restrict__ Qb, const ushort* __restrict__ Kb,
    const ushort* __restrict__ Vt,
    ushort* __restrict__ CTXhi, ushort* __restrict__ CTXlo)
{
    __shared__ __align__(16) ushort Ks[2][4096];
    __shared__ __align__(16) ushort Vs[2][4096];

    const int tid = threadIdx.x;
    const int w = tid >> 6;
    const int l = tid & 63;
    const int lm = l & 15;
    const int lq = l >> 4;
    const int q0 = blockIdx.x * 128;
    const int bh = blockIdx.y;

    const ushort* Kg = Kb + (size_t)bh * SEQ * HDIM;
    const ushort* Vg = Vt + (size_t)bh * HDIM * SEQ;

    const int srow = w * 8 + (l >> 3);
    const int sc_ = (l & 7) ^ ((l >> 3) & 7);

    bf16x8 qf[2][2];
#pragma unroll
    for (int rt = 0; rt < 2; ++rt)
#pragma unroll
        for (int kt = 0; kt < 2; ++kt)
            qf[rt][kt] = *(const bf16x8*)&Qb[((size_t)bh * SEQ + q0 + w * 32 + rt * 16 + lm) * HDIM + kt * 32 + lq * 8];

    int koff[4][2];
#pragma unroll
    for (int t = 0; t < 4; ++t)
#pragma unroll
        for (int kt = 0; kt < 2; ++kt)
            koff[t][kt] = (t * 16 + lm) * 64 + (((kt * 4 + lq) ^ (lm & 7)) << 3);

    f32x4 o[2][4] = {};
    float l_[2] = {0.0f, 0.0f};

    {
        ushort* kb = &Ks[0][0];
        ushort* vb = &Vs[0][0];
#pragma unroll
        for (int p = 0; p < 2; ++p) {
            const int row = p * 32 + srow;
            gld16(Kg + (size_t)row * HDIM + sc_ * 8, kb + (p * 32 + w * 8) * 64);
            gld16(Vg + (size_t)row * SEQ + sc_ * 8, vb + (p * 32 + w * 8) * 64);
        }
    }

    for (int ch = 0; ch < SEQ / 64; ++ch) {
        __syncthreads();

        if (ch + 1 < SEQ / 64) {
            const int kc = (ch + 1) * 64;
            ushort* kb = &Ks[(ch + 1) & 1][0];
            ushort* vb = &Vs[(ch + 1) & 1][0];
#pragma unroll
            for (int p = 0; p < 2; ++p) {
                const int row = p * 32 + srow;
                gld16(Kg + (size_t)(kc + row) * HDIM + sc_ * 8, kb + (p * 32 + w * 8) * 64);
                gld16(Vg + (size_t)row * SEQ + kc + sc_ * 8, vb + (p * 32 + w * 8) * 64);
            }
        }

        const ushort* kb = &Ks[ch & 1][0];
        const ushort* vb = &Vs[ch & 1][0];

        f32x4 st[2][4] = {};
#pragma unroll
        for (int ct = 0; ct < 4; ++ct)
#pragma unroll
            for (int kt = 0; kt < 2; ++kt) {
                const bf16x8 kf = *(const bf16x8*)&kb[koff[ct][kt]];
#pragma unroll
                for (int rt = 0; rt < 2; ++rt)
                    st[rt][ct] = __builtin_amdgcn_mfma_f32_16x16x32_bf16(kf, qf[rt][kt], st[rt][ct], 0, 0, 0);
            }

#pragma unroll
        for (int rt = 0; rt < 2; ++rt) {
            float ls = 0.0f;
#pragma unroll
            for (int ct = 0; ct < 4; ++ct)
#pragma unroll
                for (int r = 0; r < 4; ++r) {
                    const float p = __builtin_amdgcn_exp2f(st[rt][ct][r]);
                    st[rt][ct][r] = p;
                    ls += p;
                }
            ls += __shfl_xor(ls, 16, 64);
            ls += __shfl_xor(ls, 32, 64);
            l_[rt] += ls;
        }

        bf16x8 pf[2][2];
#pragma unroll
        for (int rt = 0; rt < 2; ++rt)
#pragma unroll
            for (int kt2 = 0; kt2 < 2; ++kt2) {
                union { bf16x8 v; ushort u[8]; } pk;
#pragma unroll
                for (int t = 0; t < 2; ++t)
#pragma unroll
                    for (int r = 0; r < 4; ++r)
                        pk.u[t * 4 + r] = f2bf(st[rt][kt2 * 2 + t][r]);
                pf[rt][kt2] = pk.v;
            }

#pragma unroll
        for (int dt = 0; dt < 4; ++dt)
#pragma unroll
            for (int kt2 = 0; kt2 < 2; ++kt2) {
                const bf16x8 vf = *(const bf16x8*)&vb[koff[dt][kt2]];
#pragma unroll
                for (int rt = 0; rt < 2; ++rt)
                    o[rt][dt] = __builtin_amdgcn_mfma_f32_16x16x32_bf16(pf[rt][kt2], vf, o[rt][dt], 0, 0, 0);
            }
    }

    const int b = bh >> 4;
    const int h = bh & 15;
#pragma unroll
    for (int rt = 0; rt < 2; ++rt) {
        const float linv_me = 1.0f / l_[rt];
#pragma unroll
        for (int r = 0; r < 4; ++r) {
            const float lr = __shfl(linv_me, lq * 4 + r, 64);
            const int srow_ = q0 + w * 32 + rt * 16 + lq * 4 + r;
            const size_t base = ((size_t)b * SEQ + srow_) * DIMSZ + h * HDIM;
#pragma unroll
            for (int dt = 0; dt < 4; ++dt) {
                const float v = o[rt][dt][r] * lr;
                const unsigned uv = __float_as_uint(v);
                CTXhi[base + dt * 16 + lm] = (ushort)(uv >> 16);
                const float res = v - __uint_as_float(uv & 0xFFFF0000u);
                CTXlo[base + dt * 16 + lm] = (ushort)(__float_as_uint(res) >> 16);
            }
        }
    }
}

// ---------------------------------------------------------------------------
// Output projection: pre-split bf16 operands, pure-gld16 double-buffered.
// ---------------------------------------------------------------------------
__global__ __launch_bounds__(256) void oproj_gemm(
    const ushort* __restrict__ Ahi_g, const ushort* __restrict__ Alo_g,
    const ushort* __restrict__ Bhi_g, const ushort* __restrict__ Blo_g,
    const float* __restrict__ bias, float* __restrict__ out)
{
    __shared__ __align__(16) ushort smem[2][12288];

    const int tid = threadIdx.x;
    const int wave = tid >> 6;
    const int lane = tid & 63;
    const int lm = lane & 15;
    const int lq = lane >> 4;
    const int wy = wave >> 1;
    const int wx = wave & 1;
    const int m0 = blockIdx.x * 64;
    const int n0 = blockIdx.y * 128;

    const int c = tid & 3;
    const int r0 = tid >> 2;
    const int g = c ^ swz(r0 & 15);
    const ushort* gah = Ahi_g + (size_t)(m0 + r0) * DIMSZ + g * 8;
    const ushort* gal = Alo_g + (size_t)(m0 + r0) * DIMSZ + g * 8;
    const ushort* gbh = Bhi_g + (size_t)(n0 + r0) * DIMSZ + g * 8;
    const ushort* gbl = Blo_g + (size_t)(n0 + r0) * DIMSZ + g * 8;
    const int wofs = wave * 512;

    const int fo = lm * 32 + (((lq ^ swz(lm)) & 3) << 3);
    int aofs[2], bofs[4];
#pragma unroll
    for (int i = 0; i < 2; ++i) aofs[i] = (wy * 32 + i * 16) * 32 + fo;
#pragma unroll
    for (int j = 0; j < 4; ++j) bofs[j] = (wx * 64 + j * 16) * 32 + fo;

    f32x4 acc[2][4] = {};

    {
        ushort* b0 = &smem[0][0];
        gld16(gah, b0 + wofs);
        gld16(gal, b0 + 2048 + wofs);
        gld16(gbh, b0 + 4096 + wofs);   gld16(gbh + 64 * DIMSZ, b0 + 4096 + 2048 + wofs);
        gld16(gbl, b0 + 8192 + wofs);   gld16(gbl + 64 * DIMSZ, b0 + 8192 + 2048 + wofs);
    }

    for (int kk = 0; kk < 32; ++kk) {
        __syncthreads();

        if (kk + 1 < 32) {
            const int k0 = (kk + 1) * 32;
            ushort* nb = &smem[(kk + 1) & 1][0];
            gld16(gah + k0, nb + wofs);
            gld16(gal + k0, nb + 2048 + wofs);
            gld16(gbh + k0, nb + 4096 + wofs);   gld16(gbh + 64 * DIMSZ + k0, nb + 4096 + 2048 + wofs);
            gld16(gbl + k0, nb + 8192 + wofs);   gld16(gbl + 64 * DIMSZ + k0, nb + 8192 + 2048 + wofs);
        }

        const ushort* Ah = &smem[kk & 1][0];
        const ushort* Al = Ah + 2048;
        const ushort* Bh = Ah + 4096;
        const ushort* Bl = Ah + 8192;

        bf16x8 ahf[2], alf[2], bhf[4], blf[4];
#pragma unroll
        for (int i = 0; i < 2; ++i) {
            ahf[i] = *(const bf16x8*)&Ah[aofs[i]];
            alf[i] = *(const bf16x8*)&Al[aofs[i]];
        }
#pragma unroll
        for (int j = 0; j < 4; ++j) {
            bhf[j] = *(const bf16x8*)&Bh[bofs[j]];
            blf[j] = *(const bf16x8*)&Bl[bofs[j]];
        }
#pragma unroll
        for (int i = 0; i < 2; ++i)
#pragma unroll
            for (int j = 0; j < 4; ++j) {
                acc[i][j] = __builtin_amdgcn_mfma_f32_16x16x32_bf16(ahf[i], bhf[j], acc[i][j], 0, 0, 0);
                acc[i][j] = __builtin_amdgcn_mfma_f32_16x16x32_bf16(ahf[i], blf[j], acc[i][j], 0, 0, 0);
                acc[i][j] = __builtin_amdgcn_mfma_f32_16x16x32_bf16(alf[i], bhf[j], acc[i][j], 0, 0, 0);
            }
    }

#pragma unroll
    for (int j = 0; j < 4; ++j) {
        const int nc = n0 + wx * 64 + j * 16 + lm;
        const float bb = bias[nc];
#pragma unroll
        for (int i = 0; i < 2; ++i) {
            const int mb = m0 + wy * 32 + i * 16 + lq * 4;
#pragma unroll
            for (int rr = 0; rr < 4; ++rr)
                out[(size_t)(mb + rr) * DIMSZ + nc] = acc[i][j][rr] + bb;
        }
    }
}

// ---------------------------------------------------------------------------
extern "C" void kernel_launch(void* const* d_in, const int* in_sizes, int n_in,
                              void* d_out, int out_size, void* d_ws, size_t ws_size,
                              hipStream_t stream)
{
    const float* x  = (const float*)d_in[0];
    const float* Wq = (const float*)d_in[1];
    const float* bq = (const float*)d_in[2];
    const float* Wk = (const float*)d_in[3];
    const float* bk = (const float*)d_in[4];
    const float* Wv = (const float*)d_in[5];
    const float* bv = (const float*)d_in[6];
    const float* Wo = (const float*)d_in[7];
    const float* bo = (const float*)d_in[8];
    float* out = (float*)d_out;

    const size_t elems = (size_t)NROWS * DIMSZ;   // 4M
    ushort* Qb    = (ushort*)d_ws;                // 8MB
    ushort* Kb    = Qb + elems;                   // 8MB
    ushort* Vt    = Kb + elems;                   // 8MB
    ushort* CTXhi = Vt + elems;                   // 8MB  (overlay: Xhi)
    ushort* CTXlo = CTXhi + elems;                // 8MB  (overlay: Xlo)
    ushort* Whi   = CTXlo + elems;                // 6MB
    ushort* Wlo   = Whi + 3 * (1 << 20);          // 6MB
    ushort* Wohi  = Wlo + 3 * (1 << 20);          // 2MB
    ushort* Wolo  = Wohi + (1 << 20);             // 2MB  (peak 56MB)
    ushort* Xhi   = CTXhi;                        // dead before flash writes CTX
    ushort* Xlo   = CTXlo;

    convert_all<<<4096, 256, 0, stream>>>(x, Wq, Wk, Wv, Wo,
                                          Xhi, Xlo, Whi, Wlo, Wohi, Wolo);

    qkv_gemm<<<dim3(32, 24), 256, 0, stream>>>(Xhi, Xlo, Whi, Wlo, bq, bk, bv, Qb, Kb, Vt);

    flash_attn_mfma<<<dim3(SEQ / 128, BATCH * NHEAD), 256, 0, stream>>>(Qb, Kb, Vt, CTXhi, CTXlo);

    oproj_gemm<<<dim3(64, 8), 256, 0, stream>>>(CTXhi, CTXlo, Wohi, Wolo, bo, out);
}